// Round 10
// baseline (2707.639 us; speedup 1.0000x reference)
//
#include <hip/hip_runtime.h>

// LSTM_77893526880768: B=T=F=H=256.  256 independent row-chains, 255 steps.
//
// v19 = v17 compute, restructured so ALL weights fit registers WITHOUT spill.
//
// Evidence ladder:
//   v9 4.78us/step | v12 5.24 | v14 4.42 | v15 2.85 | v16 2.35 | v17 2.34
//   (XCD swizzle: FETCH 525->68MB, dur unchanged -> L3 masked it) |
//   v18 6.4us/step REGRESSION: o-weights->regs made 256 weight regs +
//   working > unified-file budget -> scratch SPILL (WRITE_SIZE 1.5->22MB).
//   Clock FIXED ~750 MHz (5x MFMA-cycle checks).  v17 budget (1755cy):
//   MFMA 620/SIMD (invariant: per-CU work fixed at 1 row-group/CU) +
//   VALU ~414 + LDS 768/CU (o_w re-read 512 + h) + conflicts 272.
//
// v19 reconciles weight-residency with the register budget:
//   64 WGs x 1024 thr (16 waves).  WG x: rows [4x,4x+4), all 256 cols.
//   Wave w owns ONE col-block (cols 16w..16w+16) x ALL 4 gates =
//   32 frags = 128 regs (v15-17 proved 192+work fits; v18 proved 256+ not).
//   -> zero weight LDS traffic, no o_w staging, LDS = 4KB h dbuf.
//   +88KB dead spacer pins 1 WG/CU (2 WGs/CU would double per-SIMD MFMA).
//   h swizzle for 4 rows: swz(r)=((r&1)<<4)|((r&2)<<5); read addr =
//   cl*512 + (q*16 ^ swz(cl)) ^ kt*64 (XOR-associative, chunks contiguous);
//   write wb = q*512 + (col*2 ^ swz(q)).  2-way banks both sides (free).
//   Redistribute: valid C rows 0..3 at q=0,e=0..3 -> lane(q,cl) takes
//   element q from lane(0,cl) via shfl_xor(q*16).  1 cell/thread EW.
//   XCD swizzle for 64 WGs: x=(b&7)*8+(b>>3) -> each P-sharing quad
//   (same x>>2) has constant b%8 -> one XCD (v17-proven mechanism).
//
// Workspace layout:
//   [0, 512K)       WxT bf16   (dead after precompute)
//   [512K, 1M)      WhT bf16
//   [1M, 1M+4K)     bcat fp32
//   [1M+4K, ...)    P bf16  [t][rg16][n][16] = 133,693,440 B

#define STEPS 255

typedef short bf16x8 __attribute__((ext_vector_type(8)));
typedef short bf16x4 __attribute__((ext_vector_type(4)));
typedef float f32x4  __attribute__((ext_vector_type(4)));

__device__ inline unsigned short f2bf(float f) {
  unsigned int u = __float_as_uint(f);
  unsigned int r = (u + 0x7FFFu + ((u >> 16) & 1u)) >> 16;  // RNE
  return (unsigned short)r;
}
__device__ inline float bf2f(unsigned short s) {
  return __uint_as_float(((unsigned int)s) << 16);
}
__device__ inline float sig_f(float x) {
  float e = exp2f(-1.442695041f * x);
  return __builtin_amdgcn_rcpf(1.0f + e);
}
__device__ inline float tanh_f(float x) {
  float e = exp2f(-2.885390082f * x);
  return 2.0f * __builtin_amdgcn_rcpf(1.0f + e) - 1.0f;
}

// ---------- prep: W transpose (W[k][j] fp32 -> WT[g*256+j][k] bf16) ----------
__global__ __launch_bounds__(256) void lstm_prep_w(
    const float* __restrict__ m0, const float* __restrict__ m1,
    const float* __restrict__ m2, const float* __restrict__ m3,
    const float* __restrict__ m4, const float* __restrict__ m5,
    const float* __restrict__ m6, const float* __restrict__ m7,
    unsigned short* __restrict__ WxT, unsigned short* __restrict__ WhT) {
  const float* mats[8] = {m0, m1, m2, m3, m4, m5, m6, m7};
  int mat = blockIdx.z;
  const float* W = mats[mat];
  unsigned short* out = (mat < 4 ? WxT : WhT) + (size_t)(mat & 3) * 256 * 256;
  int kblk = blockIdx.x * 32, jblk = blockIdx.y * 32;
  __shared__ float tile[32][33];
  int tx = threadIdx.x & 31, ty = threadIdx.x >> 5;
#pragma unroll
  for (int i = 0; i < 4; ++i) {
    int kk = ty + i * 8;
    tile[kk][tx] = W[(size_t)(kblk + kk) * 256 + jblk + tx];
  }
  __syncthreads();
#pragma unroll
  for (int i = 0; i < 4; ++i) {
    int jj = ty + i * 8;
    out[(size_t)(jblk + jj) * 256 + kblk + tx] = f2bf(tile[tx][jj]);
  }
}

// ---------- prep: bias fold ----------
__global__ void lstm_prep_b(
    const float* __restrict__ bx0, const float* __restrict__ bx1,
    const float* __restrict__ bx2, const float* __restrict__ bx3,
    const float* __restrict__ bh0, const float* __restrict__ bh1,
    const float* __restrict__ bh2, const float* __restrict__ bh3,
    float* __restrict__ bcat) {
  const float* bx[4] = {bx0, bx1, bx2, bx3};
  const float* bh[4] = {bh0, bh1, bh2, bh3};
  int i = blockIdx.x * 256 + threadIdx.x;
  int g = i >> 8, j = i & 255;
  bcat[i] = bx[g][j] + bh[g][j];
}

// ---------- precompute: P[t][rg16][n][rl] = bcat[n] + sum_k x[r,t,k] Wx[k,n] ----------
// grid (255, 2): blockIdx.y selects 8 of the 16 n-blocks (x-frags duplicated).
__global__ __launch_bounds__(256, 1) void lstm_precompute(
    const float* __restrict__ x, const unsigned short* __restrict__ WxT,
    const float* __restrict__ bcat, unsigned short* __restrict__ P) {
  int t = blockIdx.x;
  int tid = threadIdx.x;
  int w = tid >> 6, lane = tid & 63, q = lane >> 4, cl = lane & 15;
  int rbase = w * 64;

  bf16x8 bfrag[8][4];
#pragma unroll
  for (int kt = 0; kt < 8; ++kt) {
    int k0 = kt * 32 + q * 8;
#pragma unroll
    for (int rt = 0; rt < 4; ++rt) {
      const float* xp = x + (((size_t)(rbase + rt * 16 + cl) * 256 + t) * 256 + k0);
      f32x4 lo = *(const f32x4*)xp;
      f32x4 hi = *(const f32x4*)(xp + 4);
      bf16x8 bv;
      bv[0] = (short)f2bf(lo[0]); bv[1] = (short)f2bf(lo[1]);
      bv[2] = (short)f2bf(lo[2]); bv[3] = (short)f2bf(lo[3]);
      bv[4] = (short)f2bf(hi[0]); bv[5] = (short)f2bf(hi[1]);
      bv[6] = (short)f2bf(hi[2]); bv[7] = (short)f2bf(hi[3]);
      bfrag[kt][rt] = bv;
    }
  }

  for (int nbi = 0; nbi < 8; ++nbi) {
    int nblk = (blockIdx.y * 8 + nbi) * 64;
    f32x4 acc[4][4];
#pragma unroll
    for (int a = 0; a < 4; ++a)
#pragma unroll
      for (int b = 0; b < 4; ++b) acc[a][b] = f32x4{0.f, 0.f, 0.f, 0.f};

#pragma unroll
    for (int kt = 0; kt < 8; ++kt) {
      int k0 = kt * 32 + q * 8;
      bf16x8 afrag[4];
#pragma unroll
      for (int mt = 0; mt < 4; ++mt)
        afrag[mt] = *(const bf16x8*)(WxT + (size_t)(nblk + mt * 16 + cl) * 256 + k0);
#pragma unroll
      for (int mt = 0; mt < 4; ++mt)
#pragma unroll
        for (int rt = 0; rt < 4; ++rt)
          acc[mt][rt] = __builtin_amdgcn_mfma_f32_16x16x32_bf16(
              afrag[mt], bfrag[kt][rt], acc[mt][rt], 0, 0, 0);
    }
#pragma unroll
    for (int mt = 0; mt < 4; ++mt) {
#pragma unroll
      for (int reg = 0; reg < 4; ++reg) {
        int n = nblk + mt * 16 + q * 4 + reg;
        float bb = bcat[n];
#pragma unroll
        for (int rt = 0; rt < 4; ++rt) {
          int rg16 = w * 4 + rt;  // = r>>4
          P[(((size_t)t * 16 + rg16) * 1024 + n) * 16 + cl] = f2bf(acc[mt][rt][reg] + bb);
        }
      }
    }
  }
}

// ---------- recurrent v19: 64 WGs x 1024 thr, 1 block/wave, all weights in regs ----------
__global__ __launch_bounds__(1024, 1) void lstm_recurrent(
    const unsigned short* __restrict__ WhT,
    const unsigned short* __restrict__ P,
    float* __restrict__ out) {
  // h double buffer, rows 0..3, swizzled (see header).  4 KB.
  __shared__ unsigned short hbuf[2][1024];
  // Dead spacer: total LDS ~94KB > 80KB -> exactly 1 WG/CU (2 co-resident
  // WGs would double per-SIMD MFMA issue).
  __shared__ char spacer[90112];

  int tid = threadIdx.x;
  int w = tid >> 6, lane = tid & 63, q = lane >> 4, cl = lane & 15;
  // XCD swizzle (v17 mechanism, 64-WG variant): P-sharing quad (same x>>2)
  // has constant b%8 -> one XCD -> each P line fetched into exactly one L2.
  int b_ = blockIdx.x;
  int x = (b_ & 7) * 8 + (b_ >> 3);  // bijective 0..63
  int rg16 = x >> 2;            // P row-group (global row >> 4)
  int idxb = (x & 3) * 4;       // P idx15 base for this WG's rows

  // ---- ALL 4 gates' weights for this wave's col-block into registers:
  // 32 frags = 128 regs (static indexing only -- rule #20).
  int colq = w * 16 + cl;       // this wave's cols; also lane's EW col
  bf16x8 wreg[4][8];            // [gate][kt]
#pragma unroll
  for (int g = 0; g < 4; ++g)
#pragma unroll
    for (int kt = 0; kt < 8; ++kt)
      wreg[g][kt] =
          *(const bf16x8*)(WhT + (size_t)(g * 256 + colq) * 256 + kt * 32 + q * 8);

  // ---- zero BOTH h buffers (rows 0..3; h_0 = 0); touch spacer (keep alive)
  ((unsigned int*)&hbuf[0][0])[tid] = 0;
  spacer[tid] = 0;

  // Memory clobber (v15-proven): rematerializing the weight global loads
  // across this fence is illegal => weight values stay register-resident.
  asm volatile("" ::: "memory");
  __syncthreads();

  // h A-read: row = cl (only cl<4 valid), k-chunk byte = kt*64 + q*16,
  // swizzle swz(r) = ((r&1)<<4) | ((r&2)<<5).  XOR-associative with kt*64.
  int swzc = ((cl & 1) << 4) | ((cl & 2) << 5);
  int abase = cl * 512 + ((q * 16) ^ swzc);
  bool ard = (cl < 4);  // rows 4..15 are structural zeros

  // EW ownership: lane (q,cl) owns (row q, col colq).  1 cell/thread.
  int swzq = ((q & 1) << 4) | ((q & 2) << 5);
  int idx15 = idxb + q;

  float creg = 0.f;

  for (int t = 0; t < STEPS; ++t) {
    int rb = t & 1;
    bool lastt = (t == STEPS - 1);
    const unsigned short* hr = &hbuf[rb][0];
    unsigned short* hw = &hbuf[rb ^ 1][0];

    // P loads for this lane's cell: issued at step start, consumed after
    // the MFMA phase -> L2/HBM latency stays hidden.
    unsigned short pv[4];
    {
      const unsigned short* pp =
          P + (((size_t)t * 16 + rg16) * 1024 + colq) * 16 + idx15;
#pragma unroll
      for (int g = 0; g < 4; ++g) pv[g] = pp[(size_t)g * 4096];
    }

    // ---- h A-fragments: predicated (rows 4..15 structurally zero)
    bf16x8 af[8];
#pragma unroll
    for (int kt = 0; kt < 8; ++kt) {
      bf16x8 z = {0, 0, 0, 0, 0, 0, 0, 0};
      if (ard) z = *(const bf16x8*)(hr + ((abase ^ (kt * 64)) >> 1));
      af[kt] = z;
    }

    // ---- MFMA: 4 gates x 8 kt, weights all in registers
    f32x4 acc[4];
#pragma unroll
    for (int g = 0; g < 4; ++g) acc[g] = f32x4{0.f, 0.f, 0.f, 0.f};
#pragma unroll
    for (int kt = 0; kt < 8; ++kt) {
      acc[0] = __builtin_amdgcn_mfma_f32_16x16x32_bf16(af[kt], wreg[0][kt], acc[0], 0, 0, 0);
      acc[1] = __builtin_amdgcn_mfma_f32_16x16x32_bf16(af[kt], wreg[1][kt], acc[1], 0, 0, 0);
      acc[2] = __builtin_amdgcn_mfma_f32_16x16x32_bf16(af[kt], wreg[2][kt], acc[2], 0, 0, 0);
      acc[3] = __builtin_amdgcn_mfma_f32_16x16x32_bf16(af[kt], wreg[3][kt], acc[3], 0, 0, 0);
    }

    // ---- redistribute: valid C rows 0..3 at q=0, e=0..3.
    // Lane (q,cl) takes element q from lane (0,cl) via shfl_xor(q*16).
    float sh1[4], sh2[4], sh3[4], ag[4];
#pragma unroll
    for (int g = 0; g < 4; ++g) {
      sh1[g] = __shfl_xor(acc[g][1], 16, 64);  // q=1 <- q=0: row 1
      sh2[g] = __shfl_xor(acc[g][2], 32, 64);  // q=2 <- q=0: row 2
      sh3[g] = __shfl_xor(acc[g][3], 48, 64);  // q=3 <- q=0: row 3
    }
#pragma unroll
    for (int g = 0; g < 4; ++g)
      ag[g] = (q == 0) ? acc[g][0]
            : (q == 1) ? sh1[g]
            : (q == 2) ? sh2[g]
                       : sh3[g];

    // ---- EW: exactly one LSTM cell per lane.
    {
      float pi = ag[0] + bf2f(pv[0]);
      float pf = ag[1] + bf2f(pv[1]);
      float pg = ag[2] + bf2f(pv[2]);
      float po = ag[3] + bf2f(pv[3]);
      float ig = sig_f(pi), fg = sig_f(pf), gg = tanh_f(pg), og = sig_f(po);
      float cn = fg * creg + ig * gg;
      creg = cn;
      float hn = og * tanh_f(cn);
      if (!lastt) {
        int wb = q * 512 + ((colq * 2) ^ swzq);
        hw[wb >> 1] = f2bf(hn);
      } else {
        out[(size_t)(x * 4 + q) * 256 + colq] = hn;
        out[65536 + (size_t)(x * 4 + q) * 256 + colq] = cn;
      }
    }

    __syncthreads();  // h(t+1) complete before step t+1 reads it
  }
}

extern "C" void kernel_launch(void* const* d_in, const int* in_sizes, int n_in,
                              void* d_out, int out_size, void* d_ws, size_t ws_size,
                              hipStream_t stream) {
  const float* x = (const float*)d_in[0];
  const float* wx0 = (const float*)d_in[1];
  const float* wx1 = (const float*)d_in[5];
  const float* wx2 = (const float*)d_in[9];
  const float* wx3 = (const float*)d_in[13];
  const float* wh0 = (const float*)d_in[3];
  const float* wh1 = (const float*)d_in[7];
  const float* wh2 = (const float*)d_in[11];
  const float* wh3 = (const float*)d_in[15];
  const float* bx0 = (const float*)d_in[2];
  const float* bx1 = (const float*)d_in[6];
  const float* bx2 = (const float*)d_in[10];
  const float* bx3 = (const float*)d_in[14];
  const float* bh0 = (const float*)d_in[4];
  const float* bh1 = (const float*)d_in[8];
  const float* bh2 = (const float*)d_in[12];
  const float* bh3 = (const float*)d_in[16];

  char* ws = (char*)d_ws;
  unsigned short* WxT = (unsigned short*)(ws + 0);          // dead after precompute
  unsigned short* WhT = (unsigned short*)(ws + 524288);
  float* bcat = (float*)(ws + 1048576);
  unsigned short* P = (unsigned short*)(ws + 1052672);      // [t][rg16][n][16] bf16

  lstm_prep_w<<<dim3(8, 8, 8), 256, 0, stream>>>(wx0, wx1, wx2, wx3,
                                                 wh0, wh1, wh2, wh3, WxT, WhT);
  lstm_prep_b<<<4, 256, 0, stream>>>(bx0, bx1, bx2, bx3, bh0, bh1, bh2, bh3, bcat);
  lstm_precompute<<<dim3(255, 2), 256, 0, stream>>>(x, WxT, bcat, P);
  lstm_recurrent<<<dim3(64), 1024, 0, stream>>>(WhT, P, (float*)d_out);
}

// Round 11
// 873.543 us; speedup vs baseline: 3.0996x; 3.0996x over previous
//
#include <hip/hip_runtime.h>

// LSTM_77893526880768: B=T=F=H=256.  256 independent row-chains, 255 steps.
//
// v20 = v17 (best verified: 596us recurrent) + predicated h reads + 2KB hbuf.
//
// Evidence ladder:
//   v9 4.78us/step | v12 5.24 | v14 4.42 | v15 2.85 | v16 2.35 | v17 2.34 |
//   v18 6.4 SPILL (+64 weight regs) | v19 9.6 SPILL (128 regs @1024thr).
//   Clock FIXED ~750 MHz (5x MFMA-cycle checks).
//   REGISTER-PLACEMENT OPTIMUM (falsified twice beyond): 512-thr blocks,
//   192 fragment-regs (i,f,g via v15 clobber-pin), o-gate from LDS.
//   v17 step budget (1755cy): MFMA 620/SIMD (floor) + VALU 414 + LDS 768
//   (o_w 512 must stay + h 256) + conflicts ~270.
//   v18/v19 validated IN ISOLATION (both passed correctness):
//     - predicated h-read (cl<2; rows 2..15 structurally zero)
//     - conflicts collapse 8.88M -> 0.52M with it
//   v20 takes exactly those two deltas on the v17 base: removes ~450cy
//   (h LDS bandwidth + conflict stall) at zero register cost.
//
// Workspace layout:
//   [0, 512K)       WxT bf16   (dead after precompute)
//   [512K, 1M)      WhT bf16
//   [1M, 1M+4K)     bcat fp32
//   [1M+4K, ...)    P bf16  [t][rg16][n][16] = 133,693,440 B

#define STEPS 255

typedef short bf16x8 __attribute__((ext_vector_type(8)));
typedef short bf16x4 __attribute__((ext_vector_type(4)));
typedef float f32x4  __attribute__((ext_vector_type(4)));

__device__ inline unsigned short f2bf(float f) {
  unsigned int u = __float_as_uint(f);
  unsigned int r = (u + 0x7FFFu + ((u >> 16) & 1u)) >> 16;  // RNE
  return (unsigned short)r;
}
__device__ inline float bf2f(unsigned short s) {
  return __uint_as_float(((unsigned int)s) << 16);
}
__device__ inline float sig_f(float x) {
  float e = exp2f(-1.442695041f * x);
  return __builtin_amdgcn_rcpf(1.0f + e);
}
__device__ inline float tanh_f(float x) {
  float e = exp2f(-2.885390082f * x);
  return 2.0f * __builtin_amdgcn_rcpf(1.0f + e) - 1.0f;
}

// ---------- prep: W transpose (W[k][j] fp32 -> WT[g*256+j][k] bf16) ----------
__global__ __launch_bounds__(256) void lstm_prep_w(
    const float* __restrict__ m0, const float* __restrict__ m1,
    const float* __restrict__ m2, const float* __restrict__ m3,
    const float* __restrict__ m4, const float* __restrict__ m5,
    const float* __restrict__ m6, const float* __restrict__ m7,
    unsigned short* __restrict__ WxT, unsigned short* __restrict__ WhT) {
  const float* mats[8] = {m0, m1, m2, m3, m4, m5, m6, m7};
  int mat = blockIdx.z;
  const float* W = mats[mat];
  unsigned short* out = (mat < 4 ? WxT : WhT) + (size_t)(mat & 3) * 256 * 256;
  int kblk = blockIdx.x * 32, jblk = blockIdx.y * 32;
  __shared__ float tile[32][33];
  int tx = threadIdx.x & 31, ty = threadIdx.x >> 5;
#pragma unroll
  for (int i = 0; i < 4; ++i) {
    int kk = ty + i * 8;
    tile[kk][tx] = W[(size_t)(kblk + kk) * 256 + jblk + tx];
  }
  __syncthreads();
#pragma unroll
  for (int i = 0; i < 4; ++i) {
    int jj = ty + i * 8;
    out[(size_t)(jblk + jj) * 256 + kblk + tx] = f2bf(tile[tx][jj]);
  }
}

// ---------- prep: bias fold ----------
__global__ void lstm_prep_b(
    const float* __restrict__ bx0, const float* __restrict__ bx1,
    const float* __restrict__ bx2, const float* __restrict__ bx3,
    const float* __restrict__ bh0, const float* __restrict__ bh1,
    const float* __restrict__ bh2, const float* __restrict__ bh3,
    float* __restrict__ bcat) {
  const float* bx[4] = {bx0, bx1, bx2, bx3};
  const float* bh[4] = {bh0, bh1, bh2, bh3};
  int i = blockIdx.x * 256 + threadIdx.x;
  int g = i >> 8, j = i & 255;
  bcat[i] = bx[g][j] + bh[g][j];
}

// ---------- precompute: P[t][rg16][n][rl] = bcat[n] + sum_k x[r,t,k] Wx[k,n] ----------
// grid (255, 2): blockIdx.y selects 8 of the 16 n-blocks (x-frags duplicated).
__global__ __launch_bounds__(256, 1) void lstm_precompute(
    const float* __restrict__ x, const unsigned short* __restrict__ WxT,
    const float* __restrict__ bcat, unsigned short* __restrict__ P) {
  int t = blockIdx.x;
  int tid = threadIdx.x;
  int w = tid >> 6, lane = tid & 63, q = lane >> 4, cl = lane & 15;
  int rbase = w * 64;

  bf16x8 bfrag[8][4];
#pragma unroll
  for (int kt = 0; kt < 8; ++kt) {
    int k0 = kt * 32 + q * 8;
#pragma unroll
    for (int rt = 0; rt < 4; ++rt) {
      const float* xp = x + (((size_t)(rbase + rt * 16 + cl) * 256 + t) * 256 + k0);
      f32x4 lo = *(const f32x4*)xp;
      f32x4 hi = *(const f32x4*)(xp + 4);
      bf16x8 bv;
      bv[0] = (short)f2bf(lo[0]); bv[1] = (short)f2bf(lo[1]);
      bv[2] = (short)f2bf(lo[2]); bv[3] = (short)f2bf(lo[3]);
      bv[4] = (short)f2bf(hi[0]); bv[5] = (short)f2bf(hi[1]);
      bv[6] = (short)f2bf(hi[2]); bv[7] = (short)f2bf(hi[3]);
      bfrag[kt][rt] = bv;
    }
  }

  for (int nbi = 0; nbi < 8; ++nbi) {
    int nblk = (blockIdx.y * 8 + nbi) * 64;
    f32x4 acc[4][4];
#pragma unroll
    for (int a = 0; a < 4; ++a)
#pragma unroll
      for (int b = 0; b < 4; ++b) acc[a][b] = f32x4{0.f, 0.f, 0.f, 0.f};

#pragma unroll
    for (int kt = 0; kt < 8; ++kt) {
      int k0 = kt * 32 + q * 8;
      bf16x8 afrag[4];
#pragma unroll
      for (int mt = 0; mt < 4; ++mt)
        afrag[mt] = *(const bf16x8*)(WxT + (size_t)(nblk + mt * 16 + cl) * 256 + k0);
#pragma unroll
      for (int mt = 0; mt < 4; ++mt)
#pragma unroll
        for (int rt = 0; rt < 4; ++rt)
          acc[mt][rt] = __builtin_amdgcn_mfma_f32_16x16x32_bf16(
              afrag[mt], bfrag[kt][rt], acc[mt][rt], 0, 0, 0);
    }
#pragma unroll
    for (int mt = 0; mt < 4; ++mt) {
#pragma unroll
      for (int reg = 0; reg < 4; ++reg) {
        int n = nblk + mt * 16 + q * 4 + reg;
        float bb = bcat[n];
#pragma unroll
        for (int rt = 0; rt < 4; ++rt) {
          int rg16 = w * 4 + rt;  // = r>>4
          P[(((size_t)t * 16 + rg16) * 1024 + n) * 16 + cl] = f2bf(acc[mt][rt][reg] + bb);
        }
      }
    }
  }
}

// ---------- recurrent v20: v17 base + predicated h reads + 2KB hbuf ----------
__global__ __launch_bounds__(512, 2) void lstm_recurrent(
    const unsigned short* __restrict__ WhT,
    const unsigned short* __restrict__ P,
    float* __restrict__ out) {
  // o-gate B-frags: [wave][block][kt][lane] bf16x8 = 128 KB (v5-proven layout)
  __shared__ bf16x8 o_w[8][2][8][64];
  // h double buffer, rows 0..1 only, XOR-swizzled: byte ^= (row<<4).  2 KB.
  __shared__ unsigned short hbuf[2][512];

  int tid = threadIdx.x;
  int w = tid >> 6, lane = tid & 63, q = lane >> 4, cl = lane & 15;
  // XCD swizzle (v17-proven): the 8 WGs sharing P lines (same x>>3) get
  // identical b%8 -> one XCD -> each P line fetched into exactly one L2.
  int b_ = blockIdx.x;
  int x = (b_ & 7) * 16 + (b_ >> 3);  // bijective 0..127
  int rg16 = x >> 3;            // P row-group (global row >> 4)
  int idxb = (x & 7) * 2;       // P idx15 base for this WG's rows

  // ---- stage o-gate tiles into LDS: 8192 16B-chunks, 16 per thread
  for (int i = 0; i < 16; ++i) {
    int idx = tid + i * 512;
    int sw = idx >> 10, sb = (idx >> 9) & 1, skt = (idx >> 6) & 7, sl = idx & 63;
    int sq = sl >> 4, scl = sl & 15;
    int col = (2 * sw + sb) * 16 + scl;
    int k0 = skt * 32 + sq * 8;
    o_w[sw][sb][skt][sl] = *(const bf16x8*)(WhT + (size_t)(3 * 256 + col) * 256 + k0);
  }

  // ---- i,f,g gate tiles into VGPRs (static indexing only -- rule #20)
  bf16x8 wreg[2][3][8];  // [block][gate][kt] = 48 frags
#pragma unroll
  for (int b = 0; b < 2; ++b)
#pragma unroll
    for (int g = 0; g < 3; ++g)
#pragma unroll
      for (int kt = 0; kt < 8; ++kt) {
        int col = (2 * w + b) * 16 + cl;
        wreg[b][g][kt] =
            *(const bf16x8*)(WhT + (size_t)(g * 256 + col) * 256 + kt * 32 + q * 8);
      }

  // ---- zero BOTH h buffers (rows 0..1; h_0 = 0)
  if (tid < 512) ((unsigned int*)&hbuf[0][0])[tid] = 0;

  // Memory clobber (v15-proven): rematerializing the wreg global loads
  // across this fence is illegal => weight values stay register-resident.
  asm volatile("" ::: "memory");
  __syncthreads();

  // A-read base for the 2 valid rows (row = cl in {0,1}): byte =
  // cl*512 + (q*16 ^ (cl<<4)); per kt XOR kt*64 (bit-disjoint, v12-proven).
  int abase = cl * 512 + ((q * 16) ^ ((cl & 7) << 4));
  bool ard = (cl < 2);  // only these lanes read h; rows 2..15 are zero

  // EW ownership: lane (q,cl) owns the single cell
  //   block bq = q>>1, local row rq = q&1, col = 32w + bq*16 + cl.
  int bq = q >> 1, rq = q & 1;
  int colq = 32 * w + bq * 16 + cl;
  int idx15 = idxb + rq;

  float creg = 0.f;

  for (int t = 0; t < STEPS; ++t) {
    int rb = t & 1;
    bool lastt = (t == STEPS - 1);
    const unsigned short* hr = &hbuf[rb][0];
    unsigned short* hw = &hbuf[rb ^ 1][0];

    // P loads for this lane's cell: issued at step start, consumed after
    // the MFMA phase -> L2/HBM latency stays hidden.
    unsigned short pv[4];
    {
      const unsigned short* pp =
          P + (((size_t)t * 16 + rg16) * 1024 + colq) * 16 + idx15;
#pragma unroll
      for (int g = 0; g < 4; ++g) pv[g] = pp[(size_t)g * 4096];
    }

    // ---- MFMA: af loaded once per kt (predicated: rows 2..15 are zero),
    // feeds both blocks x 4 gates.
    f32x4 acc[2][4];
#pragma unroll
    for (int b = 0; b < 2; ++b)
#pragma unroll
      for (int g = 0; g < 4; ++g) acc[b][g] = f32x4{0.f, 0.f, 0.f, 0.f};

#pragma unroll
    for (int kt = 0; kt < 8; ++kt) {
      bf16x8 af = {0, 0, 0, 0, 0, 0, 0, 0};
      if (ard) af = *(const bf16x8*)(hr + ((abase ^ (kt * 64)) >> 1));
      acc[0][0] = __builtin_amdgcn_mfma_f32_16x16x32_bf16(af, wreg[0][0][kt], acc[0][0], 0, 0, 0);
      acc[0][1] = __builtin_amdgcn_mfma_f32_16x16x32_bf16(af, wreg[0][1][kt], acc[0][1], 0, 0, 0);
      acc[0][2] = __builtin_amdgcn_mfma_f32_16x16x32_bf16(af, wreg[0][2][kt], acc[0][2], 0, 0, 0);
      acc[0][3] = __builtin_amdgcn_mfma_f32_16x16x32_bf16(af, o_w[w][0][kt][lane], acc[0][3], 0, 0, 0);
      acc[1][0] = __builtin_amdgcn_mfma_f32_16x16x32_bf16(af, wreg[1][0][kt], acc[1][0], 0, 0, 0);
      acc[1][1] = __builtin_amdgcn_mfma_f32_16x16x32_bf16(af, wreg[1][1][kt], acc[1][1], 0, 0, 0);
      acc[1][2] = __builtin_amdgcn_mfma_f32_16x16x32_bf16(af, wreg[1][2][kt], acc[1][2], 0, 0, 0);
      acc[1][3] = __builtin_amdgcn_mfma_f32_16x16x32_bf16(af, o_w[w][1][kt][lane], acc[1][3], 0, 0, 0);
    }

    // ---- redistribute: valid C rows {0,1} sit at q=0, e={0,1} (per block).
    // Target: lane (q,cl) gets (block q>>1, row q&1).
    float sh1[4], sh2[4], sh3[4], ag[4];
#pragma unroll
    for (int g = 0; g < 4; ++g) {
      sh1[g] = __shfl_xor(acc[0][g][1], 16, 64);  // q=1 <- q=0: b0 row1
      sh2[g] = __shfl_xor(acc[1][g][0], 32, 64);  // q=2 <- q=0: b1 row0
      sh3[g] = __shfl_xor(acc[1][g][1], 48, 64);  // q=3 <- q=0: b1 row1
    }
#pragma unroll
    for (int g = 0; g < 4; ++g)
      ag[g] = (q == 0) ? acc[0][g][0]
            : (q == 1) ? sh1[g]
            : (q == 2) ? sh2[g]
                       : sh3[g];

    // ---- EW: exactly one LSTM cell per lane.
    {
      float pi = ag[0] + bf2f(pv[0]);
      float pf = ag[1] + bf2f(pv[1]);
      float pg = ag[2] + bf2f(pv[2]);
      float po = ag[3] + bf2f(pv[3]);
      float ig = sig_f(pi), fg = sig_f(pf), gg = tanh_f(pg), og = sig_f(po);
      float cn = fg * creg + ig * gg;
      creg = cn;
      float hn = og * tanh_f(cn);
      if (!lastt) {
        int wb = rq * 512 + ((colq * 2) ^ (rq << 4));
        hw[wb >> 1] = f2bf(hn);
      } else {
        out[(size_t)(x * 2 + rq) * 256 + colq] = hn;
        out[65536 + (size_t)(x * 2 + rq) * 256 + colq] = cn;
      }
    }

    __syncthreads();  // h(t+1) complete before step t+1 reads it
  }
}

extern "C" void kernel_launch(void* const* d_in, const int* in_sizes, int n_in,
                              void* d_out, int out_size, void* d_ws, size_t ws_size,
                              hipStream_t stream) {
  const float* x = (const float*)d_in[0];
  const float* wx0 = (const float*)d_in[1];
  const float* wx1 = (const float*)d_in[5];
  const float* wx2 = (const float*)d_in[9];
  const float* wx3 = (const float*)d_in[13];
  const float* wh0 = (const float*)d_in[3];
  const float* wh1 = (const float*)d_in[7];
  const float* wh2 = (const float*)d_in[11];
  const float* wh3 = (const float*)d_in[15];
  const float* bx0 = (const float*)d_in[2];
  const float* bx1 = (const float*)d_in[6];
  const float* bx2 = (const float*)d_in[10];
  const float* bx3 = (const float*)d_in[14];
  const float* bh0 = (const float*)d_in[4];
  const float* bh1 = (const float*)d_in[8];
  const float* bh2 = (const float*)d_in[12];
  const float* bh3 = (const float*)d_in[16];

  char* ws = (char*)d_ws;
  unsigned short* WxT = (unsigned short*)(ws + 0);          // dead after precompute
  unsigned short* WhT = (unsigned short*)(ws + 524288);
  float* bcat = (float*)(ws + 1048576);
  unsigned short* P = (unsigned short*)(ws + 1052672);      // [t][rg16][n][16] bf16

  lstm_prep_w<<<dim3(8, 8, 8), 256, 0, stream>>>(wx0, wx1, wx2, wx3,
                                                 wh0, wh1, wh2, wh3, WxT, WhT);
  lstm_prep_b<<<4, 256, 0, stream>>>(bx0, bx1, bx2, bx3, bh0, bh1, bh2, bh3, bcat);
  lstm_precompute<<<dim3(255, 2), 256, 0, stream>>>(x, WxT, bcat, P);
  lstm_recurrent<<<dim3(128), 512, 0, stream>>>(WhT, P, (float*)d_out);
}

// Round 12
// 862.190 us; speedup vs baseline: 3.1404x; 1.0132x over previous
//
#include <hip/hip_runtime.h>

// LSTM_77893526880768: B=T=F=H=256.  256 independent row-chains, 255 steps.
//
// v21 = v17 structure at 1 row/WG (256 WGs, all CUs) + branch-free
//       conflict-free h reads + shuffle reduction 12->4.
//
// Evidence ladder:
//   v9 4.78us/step | v12 5.24 | v14 4.42 | v15 2.85 | v16 2.35 | v17 2.34 |
//   v18/v19 SPILL (>192 frag regs or 1024-thr) | v20 2.53 REGRESSION:
//   per-kt exec-toggle predication sits IN the MFMA issue stream (+140cy)
//   even though conflicts dropped 8.88M->0.52M => v17's h-LDS BW/conflicts
//   were OVERLAPPED under MFMA issue, not critical.  Clock FIXED ~750 MHz.
//   v17 budget: MFMA issue 620/SIMD (invariant across ALL WG shapes) +
//   VALU ~500 + ~700 residual (shuffles/selects/barrier/dep-chains).
//
// v21 shaves the residual at ZERO issue cost:
//   - 1 row/WG: valid C element is only (q=0,e=0) -> redistribution is
//     4 shfl_xor(16) + 4 selects (was 12+12).  EW cells live on q<2 lanes.
//   - h reads branch-free AND conflict-free: hbuf = 4 rows x 576B pitch;
//     lane (q,cl) reads row cl&3 at q*16 + kt*64.  Rows 1-3 are permanent
//     zeros (A rows 1-3 = 0); lanes cl>=4 read DUPLICATE rows 0-3, which
//     corrupt only C rows 4-15 -- never consumed.  No exec toggles (v20
//     lesson).  576B pitch => start banks {r*16 + q*4} tile 32 banks
//     exactly 2-way => free (m136).  4.6 KB LDS.
//   - P access via pointer increment (stride 16*1024*16/step).
//   - XCD swizzle for 256 WGs: x=(b&7)*32+(b>>3); the 16 WGs sharing a
//     P line (same x>>4) get constant b%8 -> one XCD (v17-proven mech).
//   o_w staging, wreg 192-reg pin (v15 clobber), MFMA loop, EW math:
//   byte-identical to v17.
//
// Workspace layout:
//   [0, 512K)       WxT bf16   (dead after precompute)
//   [512K, 1M)      WhT bf16
//   [1M, 1M+4K)     bcat fp32
//   [1M+4K, ...)    P bf16  [t][rg16][n][16] = 133,693,440 B

#define STEPS 255

typedef short bf16x8 __attribute__((ext_vector_type(8)));
typedef short bf16x4 __attribute__((ext_vector_type(4)));
typedef float f32x4  __attribute__((ext_vector_type(4)));

__device__ inline unsigned short f2bf(float f) {
  unsigned int u = __float_as_uint(f);
  unsigned int r = (u + 0x7FFFu + ((u >> 16) & 1u)) >> 16;  // RNE
  return (unsigned short)r;
}
__device__ inline float bf2f(unsigned short s) {
  return __uint_as_float(((unsigned int)s) << 16);
}
__device__ inline float sig_f(float x) {
  float e = exp2f(-1.442695041f * x);
  return __builtin_amdgcn_rcpf(1.0f + e);
}
__device__ inline float tanh_f(float x) {
  float e = exp2f(-2.885390082f * x);
  return 2.0f * __builtin_amdgcn_rcpf(1.0f + e) - 1.0f;
}

// ---------- prep: W transpose (W[k][j] fp32 -> WT[g*256+j][k] bf16) ----------
__global__ __launch_bounds__(256) void lstm_prep_w(
    const float* __restrict__ m0, const float* __restrict__ m1,
    const float* __restrict__ m2, const float* __restrict__ m3,
    const float* __restrict__ m4, const float* __restrict__ m5,
    const float* __restrict__ m6, const float* __restrict__ m7,
    unsigned short* __restrict__ WxT, unsigned short* __restrict__ WhT) {
  const float* mats[8] = {m0, m1, m2, m3, m4, m5, m6, m7};
  int mat = blockIdx.z;
  const float* W = mats[mat];
  unsigned short* out = (mat < 4 ? WxT : WhT) + (size_t)(mat & 3) * 256 * 256;
  int kblk = blockIdx.x * 32, jblk = blockIdx.y * 32;
  __shared__ float tile[32][33];
  int tx = threadIdx.x & 31, ty = threadIdx.x >> 5;
#pragma unroll
  for (int i = 0; i < 4; ++i) {
    int kk = ty + i * 8;
    tile[kk][tx] = W[(size_t)(kblk + kk) * 256 + jblk + tx];
  }
  __syncthreads();
#pragma unroll
  for (int i = 0; i < 4; ++i) {
    int jj = ty + i * 8;
    out[(size_t)(jblk + jj) * 256 + kblk + tx] = f2bf(tile[tx][jj]);
  }
}

// ---------- prep: bias fold ----------
__global__ void lstm_prep_b(
    const float* __restrict__ bx0, const float* __restrict__ bx1,
    const float* __restrict__ bx2, const float* __restrict__ bx3,
    const float* __restrict__ bh0, const float* __restrict__ bh1,
    const float* __restrict__ bh2, const float* __restrict__ bh3,
    float* __restrict__ bcat) {
  const float* bx[4] = {bx0, bx1, bx2, bx3};
  const float* bh[4] = {bh0, bh1, bh2, bh3};
  int i = blockIdx.x * 256 + threadIdx.x;
  int g = i >> 8, j = i & 255;
  bcat[i] = bx[g][j] + bh[g][j];
}

// ---------- precompute: P[t][rg16][n][rl] = bcat[n] + sum_k x[r,t,k] Wx[k,n] ----------
// grid (255, 2): blockIdx.y selects 8 of the 16 n-blocks (x-frags duplicated).
__global__ __launch_bounds__(256, 1) void lstm_precompute(
    const float* __restrict__ x, const unsigned short* __restrict__ WxT,
    const float* __restrict__ bcat, unsigned short* __restrict__ P) {
  int t = blockIdx.x;
  int tid = threadIdx.x;
  int w = tid >> 6, lane = tid & 63, q = lane >> 4, cl = lane & 15;
  int rbase = w * 64;

  bf16x8 bfrag[8][4];
#pragma unroll
  for (int kt = 0; kt < 8; ++kt) {
    int k0 = kt * 32 + q * 8;
#pragma unroll
    for (int rt = 0; rt < 4; ++rt) {
      const float* xp = x + (((size_t)(rbase + rt * 16 + cl) * 256 + t) * 256 + k0);
      f32x4 lo = *(const f32x4*)xp;
      f32x4 hi = *(const f32x4*)(xp + 4);
      bf16x8 bv;
      bv[0] = (short)f2bf(lo[0]); bv[1] = (short)f2bf(lo[1]);
      bv[2] = (short)f2bf(lo[2]); bv[3] = (short)f2bf(lo[3]);
      bv[4] = (short)f2bf(hi[0]); bv[5] = (short)f2bf(hi[1]);
      bv[6] = (short)f2bf(hi[2]); bv[7] = (short)f2bf(hi[3]);
      bfrag[kt][rt] = bv;
    }
  }

  for (int nbi = 0; nbi < 8; ++nbi) {
    int nblk = (blockIdx.y * 8 + nbi) * 64;
    f32x4 acc[4][4];
#pragma unroll
    for (int a = 0; a < 4; ++a)
#pragma unroll
      for (int b = 0; b < 4; ++b) acc[a][b] = f32x4{0.f, 0.f, 0.f, 0.f};

#pragma unroll
    for (int kt = 0; kt < 8; ++kt) {
      int k0 = kt * 32 + q * 8;
      bf16x8 afrag[4];
#pragma unroll
      for (int mt = 0; mt < 4; ++mt)
        afrag[mt] = *(const bf16x8*)(WxT + (size_t)(nblk + mt * 16 + cl) * 256 + k0);
#pragma unroll
      for (int mt = 0; mt < 4; ++mt)
#pragma unroll
        for (int rt = 0; rt < 4; ++rt)
          acc[mt][rt] = __builtin_amdgcn_mfma_f32_16x16x32_bf16(
              afrag[mt], bfrag[kt][rt], acc[mt][rt], 0, 0, 0);
    }
#pragma unroll
    for (int mt = 0; mt < 4; ++mt) {
#pragma unroll
      for (int reg = 0; reg < 4; ++reg) {
        int n = nblk + mt * 16 + q * 4 + reg;
        float bb = bcat[n];
#pragma unroll
        for (int rt = 0; rt < 4; ++rt) {
          int rg16 = w * 4 + rt;  // = r>>4
          P[(((size_t)t * 16 + rg16) * 1024 + n) * 16 + cl] = f2bf(acc[mt][rt][reg] + bb);
        }
      }
    }
  }
}

// ---------- recurrent v21: 256 WGs x 1 row, branch-free h reads ----------
__global__ __launch_bounds__(512, 2) void lstm_recurrent(
    const unsigned short* __restrict__ WhT,
    const unsigned short* __restrict__ P,
    float* __restrict__ out) {
  // o-gate B-frags: [wave][block][kt][lane] bf16x8 = 128 KB (v5-proven layout)
  __shared__ bf16x8 o_w[8][2][8][64];
  // h double buffer: 4 rows x 576B pitch (row 0 live, rows 1-3 permanent
  // zeros).  2 x 2304B = 4.6 KB.  576B pitch -> 2-way banks (free, m136).
  __shared__ unsigned short hbuf[2][1152];

  int tid = threadIdx.x;
  int w = tid >> 6, lane = tid & 63, q = lane >> 4, cl = lane & 15;
  // XCD swizzle: the 16 WGs sharing P lines (same x>>4) get identical b%8
  // -> one XCD -> each P line fetched into exactly one L2 (v17 mechanism).
  int b_ = blockIdx.x;
  int x = (b_ & 7) * 32 + (b_ >> 3);  // bijective 0..255
  int rg16 = x >> 4;            // P row-group (global row >> 4)
  int idx15 = x & 15;           // P row-slot

  // ---- stage o-gate tiles into LDS: 8192 16B-chunks, 16 per thread
  for (int i = 0; i < 16; ++i) {
    int idx = tid + i * 512;
    int sw = idx >> 10, sb = (idx >> 9) & 1, skt = (idx >> 6) & 7, sl = idx & 63;
    int sq = sl >> 4, scl = sl & 15;
    int col = (2 * sw + sb) * 16 + scl;
    int k0 = skt * 32 + sq * 8;
    o_w[sw][sb][skt][sl] = *(const bf16x8*)(WhT + (size_t)(3 * 256 + col) * 256 + k0);
  }

  // ---- i,f,g gate tiles into VGPRs (static indexing only -- rule #20)
  bf16x8 wreg[2][3][8];  // [block][gate][kt] = 48 frags = 192 regs
#pragma unroll
  for (int b = 0; b < 2; ++b)
#pragma unroll
    for (int g = 0; g < 3; ++g)
#pragma unroll
      for (int kt = 0; kt < 8; ++kt) {
        int col = (2 * w + b) * 16 + cl;
        wreg[b][g][kt] =
            *(const bf16x8*)(WhT + (size_t)(g * 256 + col) * 256 + kt * 32 + q * 8);
      }

  // ---- zero BOTH h buffers (rows 1-3 stay zero forever; h_0 = 0)
  for (int i = tid; i < 1152; i += 512) ((unsigned int*)&hbuf[0][0])[i] = 0;

  // Memory clobber (v15-proven): rematerializing the wreg global loads
  // across this fence is illegal => weight values stay register-resident.
  asm volatile("" ::: "memory");
  __syncthreads();

  // h A-read, branch-free: lane (q,cl) reads row cl&3 at byte
  // (cl&3)*576 + q*16 + kt*64 (additive; max 2224 < 2304).  cl=0 -> real
  // row 0; cl=1..3 -> zero rows; cl>=4 -> duplicates, corrupting only
  // C rows 4..15 which are never consumed.
  int abase = (cl & 3) * 576 + q * 16;

  // EW ownership: lanes q<2 own cell (row x, col = 32w + 16q + cl).
  // qe=q&1 keeps addresses valid on non-owner lanes (no OOB).
  int qe = q & 1;
  int colq = 32 * w + qe * 16 + cl;
  bool own = (q < 2);

  float creg = 0.f;
  const unsigned short* pp = P + ((size_t)rg16 * 1024 + colq) * 16 + idx15;

  for (int t = 0; t < STEPS; ++t) {
    int rb = t & 1;
    bool lastt = (t == STEPS - 1);
    const char* hr = (const char*)&hbuf[rb][0];
    unsigned short* hw = &hbuf[rb ^ 1][0];

    // P loads (pointer-incremented): issued at step start, consumed after
    // the MFMA phase -> L2/HBM latency stays hidden.
    unsigned short pv[4];
#pragma unroll
    for (int g = 0; g < 4; ++g) pv[g] = pp[(size_t)g * 4096];
    pp += (size_t)16 * 1024 * 16;

    // ---- MFMA: af loaded once per kt (branch-free), both blocks x 4 gates
    f32x4 acc[2][4];
#pragma unroll
    for (int b = 0; b < 2; ++b)
#pragma unroll
      for (int g = 0; g < 4; ++g) acc[b][g] = f32x4{0.f, 0.f, 0.f, 0.f};

#pragma unroll
    for (int kt = 0; kt < 8; ++kt) {
      bf16x8 af = *(const bf16x8*)(hr + abase + kt * 64);
      acc[0][0] = __builtin_amdgcn_mfma_f32_16x16x32_bf16(af, wreg[0][0][kt], acc[0][0], 0, 0, 0);
      acc[0][1] = __builtin_amdgcn_mfma_f32_16x16x32_bf16(af, wreg[0][1][kt], acc[0][1], 0, 0, 0);
      acc[0][2] = __builtin_amdgcn_mfma_f32_16x16x32_bf16(af, wreg[0][2][kt], acc[0][2], 0, 0, 0);
      acc[0][3] = __builtin_amdgcn_mfma_f32_16x16x32_bf16(af, o_w[w][0][kt][lane], acc[0][3], 0, 0, 0);
      acc[1][0] = __builtin_amdgcn_mfma_f32_16x16x32_bf16(af, wreg[1][0][kt], acc[1][0], 0, 0, 0);
      acc[1][1] = __builtin_amdgcn_mfma_f32_16x16x32_bf16(af, wreg[1][1][kt], acc[1][1], 0, 0, 0);
      acc[1][2] = __builtin_amdgcn_mfma_f32_16x16x32_bf16(af, wreg[1][2][kt], acc[1][2], 0, 0, 0);
      acc[1][3] = __builtin_amdgcn_mfma_f32_16x16x32_bf16(af, o_w[w][1][kt][lane], acc[1][3], 0, 0, 0);
    }

    // ---- redistribute: valid C element is (q=0, e=0) per block.
    // Lane (1,cl) takes block-1's value from lane (0,cl): 4 shfl + select.
    float sh[4], ag[4];
#pragma unroll
    for (int g = 0; g < 4; ++g) sh[g] = __shfl_xor(acc[1][g][0], 16, 64);
#pragma unroll
    for (int g = 0; g < 4; ++g) ag[g] = (q == 0) ? acc[0][g][0] : sh[g];

    // ---- EW: one LSTM cell on q<2 lanes (arithmetic runs on all lanes;
    // only state update + stores are guarded -- no exec toggle in the
    // MFMA stream).
    {
      float pi = ag[0] + bf2f(pv[0]);
      float pf = ag[1] + bf2f(pv[1]);
      float pg = ag[2] + bf2f(pv[2]);
      float po = ag[3] + bf2f(pv[3]);
      float ig = sig_f(pi), fg = sig_f(pf), gg = tanh_f(pg), og = sig_f(po);
      float cn = fg * creg + ig * gg;
      creg = own ? cn : creg;
      float hn = og * tanh_f(cn);
      if (own) {
        if (!lastt) {
          hw[colq] = f2bf(hn);  // row 0, no swizzle needed
        } else {
          out[(size_t)x * 256 + colq] = hn;
          out[65536 + (size_t)x * 256 + colq] = cn;
        }
      }
    }

    __syncthreads();  // h(t+1) complete before step t+1 reads it
  }
}

extern "C" void kernel_launch(void* const* d_in, const int* in_sizes, int n_in,
                              void* d_out, int out_size, void* d_ws, size_t ws_size,
                              hipStream_t stream) {
  const float* x = (const float*)d_in[0];
  const float* wx0 = (const float*)d_in[1];
  const float* wx1 = (const float*)d_in[5];
  const float* wx2 = (const float*)d_in[9];
  const float* wx3 = (const float*)d_in[13];
  const float* wh0 = (const float*)d_in[3];
  const float* wh1 = (const float*)d_in[7];
  const float* wh2 = (const float*)d_in[11];
  const float* wh3 = (const float*)d_in[15];
  const float* bx0 = (const float*)d_in[2];
  const float* bx1 = (const float*)d_in[6];
  const float* bx2 = (const float*)d_in[10];
  const float* bx3 = (const float*)d_in[14];
  const float* bh0 = (const float*)d_in[4];
  const float* bh1 = (const float*)d_in[8];
  const float* bh2 = (const float*)d_in[12];
  const float* bh3 = (const float*)d_in[16];

  char* ws = (char*)d_ws;
  unsigned short* WxT = (unsigned short*)(ws + 0);          // dead after precompute
  unsigned short* WhT = (unsigned short*)(ws + 524288);
  float* bcat = (float*)(ws + 1048576);
  unsigned short* P = (unsigned short*)(ws + 1052672);      // [t][rg16][n][16] bf16

  lstm_prep_w<<<dim3(8, 8, 8), 256, 0, stream>>>(wx0, wx1, wx2, wx3,
                                                 wh0, wh1, wh2, wh3, WxT, WhT);
  lstm_prep_b<<<4, 256, 0, stream>>>(bx0, bx1, bx2, bx3, bh0, bh1, bh2, bh3, bcat);
  lstm_precompute<<<dim3(255, 2), 256, 0, stream>>>(x, WxT, bcat, P);
  lstm_recurrent<<<dim3(256), 512, 0, stream>>>(WhT, P, (float*)d_out);
}

// Round 13
// 782.539 us; speedup vs baseline: 3.4601x; 1.1018x over previous
//
#include <hip/hip_runtime.h>

// LSTM_77893526880768: B=T=F=H=256.  256 independent row-chains, 255 steps.
//
// v22 = v17 recurrent VERBATIM (best verified: 596us) + precompute x-dedup.
//
// Evidence ladder (recurrent step time):
//   v9 4.78us | v12 5.24 | v14 4.42 | v15 2.85 | v16 2.35 | *v17 2.34* |
//   v18/v19 SPILL | v20 2.53 (predication in MFMA stream) | v21 2.50
//   (1 row/WG, conflicts=0, shuffles 12->4 -- STILL slower than v17).
//   Clock FIXED ~700-750 MHz (6x independent MFMA-cycle checks).
//   CONCLUSION: step is pinned ~1755cy by {per-CU MFMA issue 640cy
//   (512 MFMAs/CU/step, invariant across ALL WG shapes), o_w LDS 128KB/step
//   (>=512cy; regs falsified by v18/v19 spills), serial EW tail, barrier}.
//   Conflicts/shuffles/predication are overlapped, not critical.  v17 is
//   the fixed point of the register-budget analysis: 192 weight regs
//   (i,f,g) + o-gate LDS is the unique no-spill allocation at 2 waves/SIMD.
//
// v22's single change: lstm_precompute grid (255,2)->(255,1), nbi 0..15.
//   Both y-blocks built IDENTICAL x-fragments -> x was read twice.  Now
//   read once (-65MB HBM, -255 WG launches).  Same MFMA total, same regs.
//
// Workspace layout:
//   [0, 512K)       WxT bf16   (dead after precompute)
//   [512K, 1M)      WhT bf16
//   [1M, 1M+4K)     bcat fp32
//   [1M+4K, ...)    P bf16  [t][rg16][n][16] = 133,693,440 B

#define STEPS 255

typedef short bf16x8 __attribute__((ext_vector_type(8)));
typedef short bf16x4 __attribute__((ext_vector_type(4)));
typedef float f32x4  __attribute__((ext_vector_type(4)));

__device__ inline unsigned short f2bf(float f) {
  unsigned int u = __float_as_uint(f);
  unsigned int r = (u + 0x7FFFu + ((u >> 16) & 1u)) >> 16;  // RNE
  return (unsigned short)r;
}
__device__ inline float bf2f(unsigned short s) {
  return __uint_as_float(((unsigned int)s) << 16);
}
__device__ inline float sig_f(float x) {
  float e = exp2f(-1.442695041f * x);
  return __builtin_amdgcn_rcpf(1.0f + e);
}
__device__ inline float tanh_f(float x) {
  float e = exp2f(-2.885390082f * x);
  return 2.0f * __builtin_amdgcn_rcpf(1.0f + e) - 1.0f;
}

// ---------- prep: W transpose (W[k][j] fp32 -> WT[g*256+j][k] bf16) ----------
__global__ __launch_bounds__(256) void lstm_prep_w(
    const float* __restrict__ m0, const float* __restrict__ m1,
    const float* __restrict__ m2, const float* __restrict__ m3,
    const float* __restrict__ m4, const float* __restrict__ m5,
    const float* __restrict__ m6, const float* __restrict__ m7,
    unsigned short* __restrict__ WxT, unsigned short* __restrict__ WhT) {
  const float* mats[8] = {m0, m1, m2, m3, m4, m5, m6, m7};
  int mat = blockIdx.z;
  const float* W = mats[mat];
  unsigned short* out = (mat < 4 ? WxT : WhT) + (size_t)(mat & 3) * 256 * 256;
  int kblk = blockIdx.x * 32, jblk = blockIdx.y * 32;
  __shared__ float tile[32][33];
  int tx = threadIdx.x & 31, ty = threadIdx.x >> 5;
#pragma unroll
  for (int i = 0; i < 4; ++i) {
    int kk = ty + i * 8;
    tile[kk][tx] = W[(size_t)(kblk + kk) * 256 + jblk + tx];
  }
  __syncthreads();
#pragma unroll
  for (int i = 0; i < 4; ++i) {
    int jj = ty + i * 8;
    out[(size_t)(jblk + jj) * 256 + kblk + tx] = f2bf(tile[tx][jj]);
  }
}

// ---------- prep: bias fold ----------
__global__ void lstm_prep_b(
    const float* __restrict__ bx0, const float* __restrict__ bx1,
    const float* __restrict__ bx2, const float* __restrict__ bx3,
    const float* __restrict__ bh0, const float* __restrict__ bh1,
    const float* __restrict__ bh2, const float* __restrict__ bh3,
    float* __restrict__ bcat) {
  const float* bx[4] = {bx0, bx1, bx2, bx3};
  const float* bh[4] = {bh0, bh1, bh2, bh3};
  int i = blockIdx.x * 256 + threadIdx.x;
  int g = i >> 8, j = i & 255;
  bcat[i] = bx[g][j] + bh[g][j];
}

// ---------- precompute: P[t][rg16][n][rl] = bcat[n] + sum_k x[r,t,k] Wx[k,n] ----------
// v22: grid (255,1); x-fragments built ONCE, all 16 n-blocks in one WG.
__global__ __launch_bounds__(256, 1) void lstm_precompute(
    const float* __restrict__ x, const unsigned short* __restrict__ WxT,
    const float* __restrict__ bcat, unsigned short* __restrict__ P) {
  int t = blockIdx.x;
  int tid = threadIdx.x;
  int w = tid >> 6, lane = tid & 63, q = lane >> 4, cl = lane & 15;
  int rbase = w * 64;

  bf16x8 bfrag[8][4];
#pragma unroll
  for (int kt = 0; kt < 8; ++kt) {
    int k0 = kt * 32 + q * 8;
#pragma unroll
    for (int rt = 0; rt < 4; ++rt) {
      const float* xp = x + (((size_t)(rbase + rt * 16 + cl) * 256 + t) * 256 + k0);
      f32x4 lo = *(const f32x4*)xp;
      f32x4 hi = *(const f32x4*)(xp + 4);
      bf16x8 bv;
      bv[0] = (short)f2bf(lo[0]); bv[1] = (short)f2bf(lo[1]);
      bv[2] = (short)f2bf(lo[2]); bv[3] = (short)f2bf(lo[3]);
      bv[4] = (short)f2bf(hi[0]); bv[5] = (short)f2bf(hi[1]);
      bv[6] = (short)f2bf(hi[2]); bv[7] = (short)f2bf(hi[3]);
      bfrag[kt][rt] = bv;
    }
  }

  for (int nbi = 0; nbi < 16; ++nbi) {
    int nblk = nbi * 64;
    f32x4 acc[4][4];
#pragma unroll
    for (int a = 0; a < 4; ++a)
#pragma unroll
      for (int b = 0; b < 4; ++b) acc[a][b] = f32x4{0.f, 0.f, 0.f, 0.f};

#pragma unroll
    for (int kt = 0; kt < 8; ++kt) {
      int k0 = kt * 32 + q * 8;
      bf16x8 afrag[4];
#pragma unroll
      for (int mt = 0; mt < 4; ++mt)
        afrag[mt] = *(const bf16x8*)(WxT + (size_t)(nblk + mt * 16 + cl) * 256 + k0);
#pragma unroll
      for (int mt = 0; mt < 4; ++mt)
#pragma unroll
        for (int rt = 0; rt < 4; ++rt)
          acc[mt][rt] = __builtin_amdgcn_mfma_f32_16x16x32_bf16(
              afrag[mt], bfrag[kt][rt], acc[mt][rt], 0, 0, 0);
    }
#pragma unroll
    for (int mt = 0; mt < 4; ++mt) {
#pragma unroll
      for (int reg = 0; reg < 4; ++reg) {
        int n = nblk + mt * 16 + q * 4 + reg;
        float bb = bcat[n];
#pragma unroll
        for (int rt = 0; rt < 4; ++rt) {
          int rg16 = w * 4 + rt;  // = r>>4
          P[(((size_t)t * 16 + rg16) * 1024 + n) * 16 + cl] = f2bf(acc[mt][rt][reg] + bb);
        }
      }
    }
  }
}

// ---------- recurrent v22 == v17: 128 WGs x 2 rows, XCD-swizzled ----------
__global__ __launch_bounds__(512, 2) void lstm_recurrent(
    const unsigned short* __restrict__ WhT,
    const unsigned short* __restrict__ P,
    float* __restrict__ out) {
  // o-gate B-frags: [wave][block][kt][lane] bf16x8 = 128 KB (v5-proven layout)
  __shared__ bf16x8 o_w[8][2][8][64];
  // h double buffer, XOR-swizzled: byte ^= ((row&7)<<4).  16 KB.
  // Rows 0..1 live; rows 2..15 stay zero forever (A-tile zero-padding).
  __shared__ unsigned short hbuf[2][16 * 256];

  int tid = threadIdx.x;
  int w = tid >> 6, lane = tid & 63, q = lane >> 4, cl = lane & 15;
  // XCD swizzle (v17-proven): the 8 WGs sharing P lines (same x>>3) get
  // identical b%8 -> one XCD -> each P line fetched into exactly one L2.
  int b_ = blockIdx.x;
  int x = (b_ & 7) * 16 + (b_ >> 3);  // bijective 0..127
  int rg16 = x >> 3;            // P row-group (global row >> 4)
  int idxb = (x & 7) * 2;       // P idx15 base for this WG's rows

  // ---- stage o-gate tiles into LDS: 8192 16B-chunks, 16 per thread
  for (int i = 0; i < 16; ++i) {
    int idx = tid + i * 512;
    int sw = idx >> 10, sb = (idx >> 9) & 1, skt = (idx >> 6) & 7, sl = idx & 63;
    int sq = sl >> 4, scl = sl & 15;
    int col = (2 * sw + sb) * 16 + scl;
    int k0 = skt * 32 + sq * 8;
    o_w[sw][sb][skt][sl] = *(const bf16x8*)(WhT + (size_t)(3 * 256 + col) * 256 + k0);
  }

  // ---- i,f,g gate tiles into VGPRs (static indexing only -- rule #20)
  bf16x8 wreg[2][3][8];  // [block][gate][kt] = 48 frags
#pragma unroll
  for (int b = 0; b < 2; ++b)
#pragma unroll
    for (int g = 0; g < 3; ++g)
#pragma unroll
      for (int kt = 0; kt < 8; ++kt) {
        int col = (2 * w + b) * 16 + cl;
        wreg[b][g][kt] =
            *(const bf16x8*)(WhT + (size_t)(g * 256 + col) * 256 + kt * 32 + q * 8);
      }

  // ---- zero BOTH h buffers (rows 2..15 never written; h_0 = 0)
  for (int i = tid; i < 4096; i += 512) ((unsigned int*)&hbuf[0][0])[i] = 0;

  // Memory clobber (v15-proven): rematerializing the wreg global loads
  // across this fence is illegal => weight values stay register-resident.
  asm volatile("" ::: "memory");
  __syncthreads();

  // A-read base (t-independent): row = cl, k-offset q*16 within kt-block,
  // swizzled.  Per kt: byte = abase ^ (kt*64) (bit-disjoint, v12-proven).
  int abase = cl * 512 + ((q * 16) ^ ((cl & 7) << 4));

  // EW ownership: lane (q,cl) owns the single cell
  //   block bq = q>>1, local row rq = q&1, col = 32w + bq*16 + cl.
  int bq = q >> 1, rq = q & 1;
  int colq = 32 * w + bq * 16 + cl;
  int idx15 = idxb + rq;

  float creg = 0.f;

  for (int t = 0; t < STEPS; ++t) {
    int rb = t & 1;
    bool lastt = (t == STEPS - 1);
    const unsigned short* hr = &hbuf[rb][0];
    unsigned short* hw = &hbuf[rb ^ 1][0];

    // P loads for this lane's cell: issued at step start, consumed after
    // the MFMA phase -> L2/HBM latency stays hidden.
    unsigned short pv[4];
    {
      const unsigned short* pp =
          P + (((size_t)t * 16 + rg16) * 1024 + colq) * 16 + idx15;
#pragma unroll
      for (int g = 0; g < 4; ++g) pv[g] = pp[(size_t)g * 4096];
    }

    // ---- MFMA: af loaded once per kt, feeds both blocks x 4 gates
    f32x4 acc[2][4];
#pragma unroll
    for (int b = 0; b < 2; ++b)
#pragma unroll
      for (int g = 0; g < 4; ++g) acc[b][g] = f32x4{0.f, 0.f, 0.f, 0.f};

#pragma unroll
    for (int kt = 0; kt < 8; ++kt) {
      bf16x8 af = *(const bf16x8*)(hr + ((abase ^ (kt * 64)) >> 1));
      acc[0][0] = __builtin_amdgcn_mfma_f32_16x16x32_bf16(af, wreg[0][0][kt], acc[0][0], 0, 0, 0);
      acc[0][1] = __builtin_amdgcn_mfma_f32_16x16x32_bf16(af, wreg[0][1][kt], acc[0][1], 0, 0, 0);
      acc[0][2] = __builtin_amdgcn_mfma_f32_16x16x32_bf16(af, wreg[0][2][kt], acc[0][2], 0, 0, 0);
      acc[0][3] = __builtin_amdgcn_mfma_f32_16x16x32_bf16(af, o_w[w][0][kt][lane], acc[0][3], 0, 0, 0);
      acc[1][0] = __builtin_amdgcn_mfma_f32_16x16x32_bf16(af, wreg[1][0][kt], acc[1][0], 0, 0, 0);
      acc[1][1] = __builtin_amdgcn_mfma_f32_16x16x32_bf16(af, wreg[1][1][kt], acc[1][1], 0, 0, 0);
      acc[1][2] = __builtin_amdgcn_mfma_f32_16x16x32_bf16(af, wreg[1][2][kt], acc[1][2], 0, 0, 0);
      acc[1][3] = __builtin_amdgcn_mfma_f32_16x16x32_bf16(af, o_w[w][1][kt][lane], acc[1][3], 0, 0, 0);
    }

    // ---- redistribute: valid C rows {0,1} sit at q=0, e={0,1} (per block).
    // Target: lane (q,cl) gets (block q>>1, row q&1).
    float sh1[4], sh2[4], sh3[4], ag[4];
#pragma unroll
    for (int g = 0; g < 4; ++g) {
      sh1[g] = __shfl_xor(acc[0][g][1], 16, 64);  // q=1 <- q=0: b0 row1
      sh2[g] = __shfl_xor(acc[1][g][0], 32, 64);  // q=2 <- q=0: b1 row0
      sh3[g] = __shfl_xor(acc[1][g][1], 48, 64);  // q=3 <- q=0: b1 row1
    }
#pragma unroll
    for (int g = 0; g < 4; ++g)
      ag[g] = (q == 0) ? acc[0][g][0]
            : (q == 1) ? sh1[g]
            : (q == 2) ? sh2[g]
                       : sh3[g];

    // ---- EW: exactly one LSTM cell per lane.
    {
      float pi = ag[0] + bf2f(pv[0]);
      float pf = ag[1] + bf2f(pv[1]);
      float pg = ag[2] + bf2f(pv[2]);
      float po = ag[3] + bf2f(pv[3]);
      float ig = sig_f(pi), fg = sig_f(pf), gg = tanh_f(pg), og = sig_f(po);
      float cn = fg * creg + ig * gg;
      creg = cn;
      float hn = og * tanh_f(cn);
      if (!lastt) {
        int wb = rq * 512 + ((colq * 2) ^ (rq << 4));
        hw[wb >> 1] = f2bf(hn);
      } else {
        out[(size_t)(x * 2 + rq) * 256 + colq] = hn;
        out[65536 + (size_t)(x * 2 + rq) * 256 + colq] = cn;
      }
    }

    __syncthreads();  // h(t+1) complete before step t+1 reads it
  }
}

extern "C" void kernel_launch(void* const* d_in, const int* in_sizes, int n_in,
                              void* d_out, int out_size, void* d_ws, size_t ws_size,
                              hipStream_t stream) {
  const float* x = (const float*)d_in[0];
  const float* wx0 = (const float*)d_in[1];
  const float* wx1 = (const float*)d_in[5];
  const float* wx2 = (const float*)d_in[9];
  const float* wx3 = (const float*)d_in[13];
  const float* wh0 = (const float*)d_in[3];
  const float* wh1 = (const float*)d_in[7];
  const float* wh2 = (const float*)d_in[11];
  const float* wh3 = (const float*)d_in[15];
  const float* bx0 = (const float*)d_in[2];
  const float* bx1 = (const float*)d_in[6];
  const float* bx2 = (const float*)d_in[10];
  const float* bx3 = (const float*)d_in[14];
  const float* bh0 = (const float*)d_in[4];
  const float* bh1 = (const float*)d_in[8];
  const float* bh2 = (const float*)d_in[12];
  const float* bh3 = (const float*)d_in[16];

  char* ws = (char*)d_ws;
  unsigned short* WxT = (unsigned short*)(ws + 0);          // dead after precompute
  unsigned short* WhT = (unsigned short*)(ws + 524288);
  float* bcat = (float*)(ws + 1048576);
  unsigned short* P = (unsigned short*)(ws + 1052672);      // [t][rg16][n][16] bf16

  lstm_prep_w<<<dim3(8, 8, 8), 256, 0, stream>>>(wx0, wx1, wx2, wx3,
                                                 wh0, wh1, wh2, wh3, WxT, WhT);
  lstm_prep_b<<<4, 256, 0, stream>>>(bx0, bx1, bx2, bx3, bh0, bh1, bh2, bh3, bcat);
  lstm_precompute<<<dim3(255, 1), 256, 0, stream>>>(x, WxT, bcat, P);
  lstm_recurrent<<<dim3(128), 512, 0, stream>>>(WhT, P, (float*)d_out);
}